// Round 7
// baseline (367.470 us; speedup 1.0000x reference)
//
#include <hip/hip_runtime.h>
#include <hip/hip_bf16.h>

#define Bz 4
#define Sz 2048
#define Dz 1024
#define Hz 16
#define DHz 64

typedef __bf16 bf16x8 __attribute__((ext_vector_type(8)));
typedef float f32x4 __attribute__((ext_vector_type(4)));

// LDS-only barrier: wait own DS ops, then barrier. Leaves global loads in flight.
#define BAR_LGKM() asm volatile("s_waitcnt lgkmcnt(0)\n\ts_barrier" ::: "memory")

__device__ __forceinline__ unsigned pk2(float a, float b) {
    union { __hip_bfloat162 h; unsigned u; } c;
    c.h = __hip_bfloat162(__float2bfloat16(a), __float2bfloat16(b));
    return c.u;
}

// fp32 -> bf16 elementwise cast (RTN), n % 4 == 0.
__global__ __launch_bounds__(256) void cvt_f32_bf16(const float* __restrict__ src,
                                                    __hip_bfloat16* __restrict__ dst, int n) {
    int i = (blockIdx.x * 256 + threadIdx.x) * 4;
    if (i >= n) return;
    float4 f = *reinterpret_cast<const float4*>(src + i);
    dst[i + 0] = __float2bfloat16(f.x);
    dst[i + 1] = __float2bfloat16(f.y);
    dst[i + 2] = __float2bfloat16(f.z);
    dst[i + 3] = __float2bfloat16(f.w);
}

// 4 weight matrices (Dz*Dz each) -> contiguous bf16 dst in one launch.
__global__ __launch_bounds__(256) void cvt_w4(const float* __restrict__ w0, const float* __restrict__ w1,
                                              const float* __restrict__ w2, const float* __restrict__ w3,
                                              __hip_bfloat16* __restrict__ dst) {
    constexpr int WEL = Dz * Dz;  // 1<<20
    int i = (blockIdx.x * 256 + threadIdx.x) * 4;
    const int which = i >> 20;
    const float* src = (which == 0) ? w0 : (which == 1) ? w1 : (which == 2) ? w2 : w3;
    float4 f = *reinterpret_cast<const float4*>(src + (i & (WEL - 1)));
    dst[i + 0] = __float2bfloat16(f.x);
    dst[i + 1] = __float2bfloat16(f.y);
    dst[i + 2] = __float2bfloat16(f.z);
    dst[i + 3] = __float2bfloat16(f.w);
}

// async global -> LDS, 16 bytes per lane; LDS dest = uniform base + lane*16.
__device__ __forceinline__ void gl2lds16(const __hip_bfloat16* g, __hip_bfloat16* l) {
    __builtin_amdgcn_global_load_lds(
        (const __attribute__((address_space(1))) void*)g,
        (__attribute__((address_space(3))) void*)l, 16, 0, 0);
}

// Shared 128x128 GEMM block body (m97 structure, BK=32).
template <int N, int K, typename OT>
__device__ __forceinline__ void gemm128_body(const __hip_bfloat16* __restrict__ A,
                                             const __hip_bfloat16* __restrict__ W,
                                             OT* __restrict__ C, int bm, int bn,
                                             __hip_bfloat16* As, __hip_bfloat16* Bs) {
    const int tid  = threadIdx.x;
    const int wid  = tid >> 6;
    const int lane = tid & 63;
    const int quad = lane >> 4;
    const int l16  = lane & 15;
    const int wr = wid >> 1, wc = wid & 1;

    const int srow = wid * 32 + (lane >> 2);
    const int scol = (lane & 3) * 8;
    const __hip_bfloat16* gA = A + (size_t)(bm * 128 + srow) * K + scol;
    const __hip_bfloat16* gB = W + (size_t)(bn * 128 + srow) * K + scol;
    __hip_bfloat16* lA = &As[(wid * 32) * 32];
    __hip_bfloat16* lB = &Bs[(wid * 32) * 32];

    f32x4 acc[4][4] = {};

    for (int k0 = 0; k0 < K; k0 += 32) {
        __syncthreads();
        gl2lds16(gA + k0,                  lA);
        gl2lds16(gA + (size_t)16 * K + k0, lA + 16 * 32);
        gl2lds16(gB + k0,                  lB);
        gl2lds16(gB + (size_t)16 * K + k0, lB + 16 * 32);
        __syncthreads();

        bf16x8 af[4], bf[4];
#pragma unroll
        for (int mi = 0; mi < 4; ++mi)
            af[mi] = *reinterpret_cast<const bf16x8*>(&As[(wr * 64 + mi * 16 + l16) * 32 + quad * 8]);
#pragma unroll
        for (int ni = 0; ni < 4; ++ni)
            bf[ni] = *reinterpret_cast<const bf16x8*>(&Bs[(wc * 64 + ni * 16 + l16) * 32 + quad * 8]);
#pragma unroll
        for (int mi = 0; mi < 4; ++mi)
#pragma unroll
            for (int ni = 0; ni < 4; ++ni)
                acc[mi][ni] = __builtin_amdgcn_mfma_f32_16x16x32_bf16(af[mi], bf[ni], acc[mi][ni], 0, 0, 0);
    }

#pragma unroll
    for (int mi = 0; mi < 4; ++mi)
#pragma unroll
        for (int ni = 0; ni < 4; ++ni) {
            const size_t row0 = (size_t)(bm * 128 + wr * 64 + mi * 16 + quad * 4);
            const size_t col  = (size_t)(bn * 128 + wc * 64 + ni * 16 + l16);
#pragma unroll
            for (int r = 0; r < 4; ++r) {
                if constexpr (__is_same(OT, float))
                    C[(row0 + r) * N + col] = acc[mi][ni][r];
                else
                    C[(row0 + r) * N + col] = __float2bfloat16(acc[mi][ni][r]);
            }
        }
}

template <int M, int N, int K, typename OT>
__global__ __launch_bounds__(256) void gemm128(const __hip_bfloat16* __restrict__ A,
                                               const __hip_bfloat16* __restrict__ W,
                                               OT* __restrict__ C) {
    __shared__ __hip_bfloat16 As[128 * 32];
    __shared__ __hip_bfloat16 Bs[128 * 32];
    constexpr int NB = N / 128;
    gemm128_body<N, K, OT>(A, W, C, blockIdx.x / NB, blockIdx.x % NB, As, Bs);
}

// Fused QKV: which = blockIdx%3 so GEMMs sharing an A-tile are dispatch-adjacent.
template <int M, int K>
__global__ __launch_bounds__(256) void gemm_qkv(const __hip_bfloat16* __restrict__ A,
                                                const __hip_bfloat16* __restrict__ W0,
                                                const __hip_bfloat16* __restrict__ W1,
                                                const __hip_bfloat16* __restrict__ W2,
                                                __hip_bfloat16* __restrict__ C0,
                                                __hip_bfloat16* __restrict__ C1,
                                                __hip_bfloat16* __restrict__ C2) {
    __shared__ __hip_bfloat16 As[128 * 32];
    __shared__ __hip_bfloat16 Bs[128 * 32];
    constexpr int NB = Dz / 128;
    const int which = blockIdx.x % 3;
    const int rem   = blockIdx.x / 3;
    const __hip_bfloat16* W = (which == 0) ? W0 : (which == 1) ? W1 : W2;
    __hip_bfloat16*       C = (which == 0) ? C0 : (which == 1) ? C1 : C2;
    gemm128_body<Dz, K, __hip_bfloat16>(A, W, C, rem / NB, rem % NB, As, Bs);
}

#define SP 72  // VT/PT leading stride in ushorts (144B rows: 16B-aligned; 2-way banks = free)

// MFMA flash attention v4: transposed-O accumulation (no broadcast shuffles),
// deferred l-reduce, exp2-domain softmax, single lgkm barrier/iter (VT dbuf),
// K/V register prefetch, causal pairing, XCD-local mapping.
__global__ __launch_bounds__(256) void attn_mfma4(const __hip_bfloat16* __restrict__ Q,
                                                  const __hip_bfloat16* __restrict__ Km,
                                                  const __hip_bfloat16* __restrict__ Vm,
                                                  __hip_bfloat16* __restrict__ O) {
    __shared__ unsigned short VT[2][64 * SP];    // V^T dbuf: [dh][key-local 0..63]
    __shared__ unsigned short PT[4][16 * SP];    // per-wave P: [q][key-local]

    const int tid  = threadIdx.x;
    const int wid  = tid >> 6;
    const int lane = tid & 63;
    const int quad = lane >> 4;
    const int l16  = lane & 15;

    // XCD-local mapping: all 16 pair-blocks of a (b,h) share blockIdx%8 -> same XCD L2.
    const int xcd  = blockIdx.x & 7;
    const int j    = blockIdx.x >> 3;            // 0..127
    const int bh   = xcd * 8 + (j >> 4);         // 0..63
    const int pair = j & 15;
    const int h    = bh & 15;
    const int b    = bh >> 4;
    const size_t base = (size_t)b * Sz * Dz + (size_t)h * DHz;

    const int vkey = (tid & 15) * 2;
    const int vdh  = (tid >> 4) * 4;
    const __hip_bfloat16* vbase = Vm + base + vdh;
    const __hip_bfloat16* kbase = Km + base + (size_t)l16 * Dz + quad * 8;

    ushort4 va0, vb0, va1, vb1;                  // V prefetch regs
    bf16x8  kf[4][2];                            // K frags: 4 key-subtiles x 2 dh-halves

    auto loadKV = [&](int kn) {
        const __hip_bfloat16* vp = vbase + (size_t)(kn + vkey) * Dz;
        va0 = *reinterpret_cast<const ushort4*>(vp);
        vb0 = *reinterpret_cast<const ushort4*>(vp + Dz);
        va1 = *reinterpret_cast<const ushort4*>(vp + (size_t)32 * Dz);
        vb1 = *reinterpret_cast<const ushort4*>(vp + (size_t)33 * Dz);
        const __hip_bfloat16* kp = kbase + (size_t)kn * Dz;
#pragma unroll
        for (int s = 0; s < 4; ++s) {
            kf[s][0] = *reinterpret_cast<const bf16x8*>(kp + (size_t)(s * 16) * Dz);
            kf[s][1] = *reinterpret_cast<const bf16x8*>(kp + (size_t)(s * 16) * Dz + 32);
        }
    };

    constexpr float SC = 0.180336880f;  // (1/sqrt(64)) * log2(e) -> exp2-domain scores
    unsigned short* PTq = &PT[wid][l16 * SP];
    int gi = 0;                                  // global iteration (VT buffer parity)

#pragma unroll 1
    for (int p = 0; p < 2; ++p) {
        const int qblk  = (p == 0) ? pair : 31 - pair;
        const int q0    = qblk * 64 + wid * 16;
        const int niter = qblk + 1;

        const __hip_bfloat16* qp = Q + base + (size_t)(q0 + l16) * Dz + quad * 8;
        const bf16x8 qf0 = *reinterpret_cast<const bf16x8*>(qp);
        const bf16x8 qf1 = *reinterpret_cast<const bf16x8*>(qp + 32);

        float m2 = -1e30f, lp = 0.f;             // log2-domain max, per-(lane) partial sum
        f32x4 ot[4] = {};                        // O^T: col q=l16, rows dh=s*16+quad*4+r

        if (p == 0) loadKV(0);                   // p==1 tile 0 prefetched at end of p==0

#pragma unroll 1
        for (int it = 0; it < niter; ++it, ++gi) {
            const int k0 = it * 64;
            unsigned short* VTb = VT[gi & 1];

            // store prefetched V tile (transposed) into this iteration's buffer
            {
                unsigned short* vt = &VTb[vdh * SP + vkey];
                *reinterpret_cast<ushort2*>(vt + 0 * SP)      = make_ushort2(va0.x, vb0.x);
                *reinterpret_cast<ushort2*>(vt + 1 * SP)      = make_ushort2(va0.y, vb0.y);
                *reinterpret_cast<ushort2*>(vt + 2 * SP)      = make_ushort2(va0.z, vb0.z);
                *reinterpret_cast<ushort2*>(vt + 3 * SP)      = make_ushort2(va0.w, vb0.w);
                *reinterpret_cast<ushort2*>(vt + 0 * SP + 32) = make_ushort2(va1.x, vb1.x);
                *reinterpret_cast<ushort2*>(vt + 1 * SP + 32) = make_ushort2(va1.y, vb1.y);
                *reinterpret_cast<ushort2*>(vt + 2 * SP + 32) = make_ushort2(va1.z, vb1.z);
                *reinterpret_cast<ushort2*>(vt + 3 * SP + 32) = make_ushort2(va1.w, vb1.w);
            }
            BAR_LGKM();  // own stores drained + block barrier => VTb ready; prev buffer free

            // S^T = K·Q^T : 8 MFMAs (C: row=key=quad*4+r, col=q=l16)
            f32x4 st[4] = {};
#pragma unroll
            for (int s = 0; s < 4; ++s) {
                st[s] = __builtin_amdgcn_mfma_f32_16x16x32_bf16(kf[s][0], qf0, st[s], 0, 0, 0);
                st[s] = __builtin_amdgcn_mfma_f32_16x16x32_bf16(kf[s][1], qf1, st[s], 0, 0, 0);
            }

            // prefetch next K/V tile (regs dead) — stays in flight across barrier
            const bool more = (it + 1 < niter);
            if (more)        loadKV(k0 + 64);
            else if (p == 0) loadKV(0);

            // V^T fragments for PV (A-operand): V^T[dh=s*16+l16][key=half*32+quad*8+j]
            const bf16x8 vf0a = *reinterpret_cast<const bf16x8*>(&VTb[( 0 + l16) * SP + quad * 8]);
            const bf16x8 vf0b = *reinterpret_cast<const bf16x8*>(&VTb[( 0 + l16) * SP + 32 + quad * 8]);
            const bf16x8 vf1a = *reinterpret_cast<const bf16x8*>(&VTb[(16 + l16) * SP + quad * 8]);
            const bf16x8 vf1b = *reinterpret_cast<const bf16x8*>(&VTb[(16 + l16) * SP + 32 + quad * 8]);
            const bf16x8 vf2a = *reinterpret_cast<const bf16x8*>(&VTb[(32 + l16) * SP + quad * 8]);
            const bf16x8 vf2b = *reinterpret_cast<const bf16x8*>(&VTb[(32 + l16) * SP + 32 + quad * 8]);
            const bf16x8 vf3a = *reinterpret_cast<const bf16x8*>(&VTb[(48 + l16) * SP + quad * 8]);
            const bf16x8 vf3b = *reinterpret_cast<const bf16x8*>(&VTb[(48 + l16) * SP + 32 + quad * 8]);

            // softmax (exp2 domain) over 16 per-lane scores (q=l16, keys=s*16+quad*4+r)
            float sv[16];
            if (it == niter - 1) {               // block-uniform branch: diagonal tile
                const int qrow = q0 + l16;
#pragma unroll
                for (int s = 0; s < 4; ++s)
#pragma unroll
                    for (int r = 0; r < 4; ++r) {
                        const int key = k0 + s * 16 + quad * 4 + r;
                        sv[s * 4 + r] = (key <= qrow) ? st[s][r] * SC : -1e30f;
                    }
            } else {
#pragma unroll
                for (int s = 0; s < 4; ++s)
#pragma unroll
                    for (int r = 0; r < 4; ++r) sv[s * 4 + r] = st[s][r] * SC;
            }

            float tmax = sv[0];
#pragma unroll
            for (int i = 1; i < 16; ++i) tmax = fmaxf(tmax, sv[i]);
            tmax = fmaxf(tmax, __shfl_xor(tmax, 16, 64));   // reduce across quads (q=l16 group)
            tmax = fmaxf(tmax, __shfl_xor(tmax, 32, 64));
            const float mnew  = fmaxf(m2, tmax);
            const float alpha = exp2f(m2 - mnew);            // first tile: exp2(-1e30)=0
            m2 = mnew;

            float p0 = exp2f(sv[0] - mnew),  p1 = exp2f(sv[1] - mnew);
            float psum = 0.f;
            unsigned pk[8];
#pragma unroll
            for (int s = 0; s < 4; ++s) {
                const float a0 = exp2f(sv[4 * s + 0] - mnew);
                const float a1 = exp2f(sv[4 * s + 1] - mnew);
                const float a2 = exp2f(sv[4 * s + 2] - mnew);
                const float a3 = exp2f(sv[4 * s + 3] - mnew);
                psum += (a0 + a1) + (a2 + a3);
                pk[2 * s]     = pk2(a0, a1);
                pk[2 * s + 1] = pk2(a2, a3);
            }
            lp = lp * alpha + psum;              // deferred: reduce across quads at epilogue

            // P -> PT[wid][q][key] (keys quad*4+r consecutive -> 8B stores)
#pragma unroll
            for (int s = 0; s < 4; ++s) {
                uint2 u; u.x = pk[2 * s]; u.y = pk[2 * s + 1];
                *reinterpret_cast<uint2*>(PTq + s * 16 + quad * 4) = u;
            }

            // rescale O^T (per-lane, no shuffle: col q = l16 matches state lane)
#pragma unroll
            for (int s = 0; s < 4; ++s) {
                ot[s][0] *= alpha; ot[s][1] *= alpha; ot[s][2] *= alpha; ot[s][3] *= alpha;
            }

            // PV (transposed): O^T[dh][q] += V^T·P; A=V^T frags, B=P[q=l16][key=quad*8+j]
            const bf16x8 pa0 = *reinterpret_cast<const bf16x8*>(PTq + quad * 8);
            const bf16x8 pa1 = *reinterpret_cast<const bf16x8*>(PTq + 32 + quad * 8);
            ot[0] = __builtin_amdgcn_mfma_f32_16x16x32_bf16(vf0a, pa0, ot[0], 0, 0, 0);
            ot[0] = __builtin_amdgcn_mfma_f32_16x16x32_bf16(vf0b, pa1, ot[0], 0, 0, 0);
            ot[1] = __builtin_amdgcn_mfma_f32_16x16x32_bf16(vf1a, pa0, ot[1], 0, 0, 0);
            ot[1] = __builtin_amdgcn_mfma_f32_16x16x32_bf16(vf1b, pa1, ot[1], 0, 0, 0);
            ot[2] = __builtin_amdgcn_mfma_f32_16x16x32_bf16(vf2a, pa0, ot[2], 0, 0, 0);
            ot[2] = __builtin_amdgcn_mfma_f32_16x16x32_bf16(vf2b, pa1, ot[2], 0, 0, 0);
            ot[3] = __builtin_amdgcn_mfma_f32_16x16x32_bf16(vf3a, pa0, ot[3], 0, 0, 0);
            ot[3] = __builtin_amdgcn_mfma_f32_16x16x32_bf16(vf3b, pa1, ot[3], 0, 0, 0);
        }

        // epilogue: reduce l across quads; lane (l16,quad) holds O[q=q0+l16][dh=s*16+quad*4+r]
        float lt = lp;
        lt += __shfl_xor(lt, 16, 64);
        lt += __shfl_xor(lt, 32, 64);
        const float inv = 1.f / lt;
        __hip_bfloat16* op = O + base + (size_t)(q0 + l16) * Dz + quad * 4;
#pragma unroll
        for (int s = 0; s < 4; ++s) {
            uint2 u;
            u.x = pk2(ot[s][0] * inv, ot[s][1] * inv);
            u.y = pk2(ot[s][2] * inv, ot[s][3] * inv);
            *reinterpret_cast<uint2*>(op + s * 16) = u;
        }
    }
}

extern "C" void kernel_launch(void* const* d_in, const int* in_sizes, int n_in,
                              void* d_out, int out_size, void* d_ws, size_t ws_size,
                              hipStream_t stream) {
    // Inputs fp32, output fp32. Internal compute bf16.
    const float* x  = (const float*)d_in[0];
    const float* wq = (const float*)d_in[1];
    const float* wk = (const float*)d_in[2];
    const float* wv = (const float*)d_in[3];
    const float* wo = (const float*)d_in[4];
    float* out = (float*)d_out;

    constexpr int TOK = Bz * Sz * Dz;   // 8,388,608
    constexpr int WEL = Dz * Dz;        // 1,048,576

    // ws: xb | wqb | wkb | wvb | wob | Qb | Kb (56 MB). Vb in d_out scratch; Ob aliases xb.
    __hip_bfloat16* xb  = (__hip_bfloat16*)d_ws;
    __hip_bfloat16* wqb = xb  + TOK;
    __hip_bfloat16* wkb = wqb + WEL;
    __hip_bfloat16* wvb = wkb + WEL;
    __hip_bfloat16* wob = wvb + WEL;
    __hip_bfloat16* Qb  = wob + WEL;
    __hip_bfloat16* Kb  = Qb + TOK;
    __hip_bfloat16* Vb  = (__hip_bfloat16*)d_out;  // dead before final GEMM overwrites d_out
    __hip_bfloat16* Ob  = xb;                      // x dead after QKV GEMM

    cvt_f32_bf16<<<TOK / 4 / 256, 256, 0, stream>>>(x, xb, TOK);
    cvt_w4<<<4 * WEL / 4 / 256, 256, 0, stream>>>(wq, wk, wv, wo, wqb);

    constexpr int M = Bz * Sz;                       // 8192
    constexpr int GB = (M / 128) * (Dz / 128);       // 512

    gemm_qkv<M, Dz><<<3 * GB, 256, 0, stream>>>(xb, wqb, wkb, wvb, Qb, Kb, Vb);

    const int ATTN_BLOCKS = Bz * Hz * 16;            // 1024 (paired q-blocks)
    attn_mfma4<<<ATTN_BLOCKS, 256, 0, stream>>>(Qb, Kb, Vb, Ob);

    gemm128<M, Dz, Dz, float><<<GB, 256, 0, stream>>>(Ob, wob, out);
}